// Round 6
// baseline (2796.140 us; speedup 1.0000x reference)
//
#include <hip/hip_runtime.h>
#include <math.h>

// ---------------------------------------------------------------------------
// 3-layer GCN on MI355X, fused aggregate-then-GEMM form.
//   out = relu( (A_hat @ in) @ W + b ),  A_hat = D^-1/2 (A+I) D^-1/2
// Fast path (ws permitting): gather source is a prescaled bf16 buffer
//   s = bf16(dinv * h)  -> 256B rows (half the random-fetch lines of fp32),
//   no per-edge dinv load, indices broadcast via __shfl (1 VMEM per edge).
// Fallback path: round-4 fp32 fused kernel (known-good).
// CSR over dst rebuilt on-device every call.
// ---------------------------------------------------------------------------

__device__ __forceinline__ unsigned short f2bf(float f) {
  unsigned u = __float_as_uint(f);
  return (unsigned short)((u + 0x7FFFu + ((u >> 16) & 1u)) >> 16);
}
__device__ __forceinline__ float bfLo(unsigned v) {  // bits[15:0] -> float
  return __uint_as_float(v << 16);
}
__device__ __forceinline__ float bfHi(unsigned v) {  // bits[31:16] -> float
  return __uint_as_float(v & 0xFFFF0000u);
}

// ------------------------------- CSR build ---------------------------------

__global__ __launch_bounds__(256) void k_zero(int* __restrict__ cnt,
                                              int* __restrict__ fillPos, int n) {
  int i = blockIdx.x * blockDim.x + threadIdx.x;
  if (i < n) { cnt[i] = 0; fillPos[i] = 0; }
}

__global__ __launch_bounds__(256) void k_deg(const int* __restrict__ dst,
                                             int* __restrict__ cnt, int E) {
  int i = blockIdx.x * blockDim.x + threadIdx.x;
  int stride = gridDim.x * blockDim.x;
  for (; i < E; i += stride) atomicAdd(&cnt[dst[i]], 1);
}

__global__ __launch_bounds__(256) void k_dinv(const int* __restrict__ cnt,
                                              float* __restrict__ dinv, int n) {
  int i = blockIdx.x * blockDim.x + threadIdx.x;
  if (i < n) dinv[i] = rsqrtf(1.0f + (float)cnt[i]);
}

__global__ __launch_bounds__(256) void k_scan1(const int* __restrict__ cnt,
                                               int* __restrict__ exc,
                                               int* __restrict__ bsum, int n) {
  __shared__ int lds[256];
  int t = threadIdx.x;
  int base = blockIdx.x * 1024 + t * 4;
  int v0 = (base + 0 < n) ? cnt[base + 0] : 0;
  int v1 = (base + 1 < n) ? cnt[base + 1] : 0;
  int v2 = (base + 2 < n) ? cnt[base + 2] : 0;
  int v3 = (base + 3 < n) ? cnt[base + 3] : 0;
  int sum = v0 + v1 + v2 + v3;
  lds[t] = sum;
  __syncthreads();
  for (int off = 1; off < 256; off <<= 1) {
    int val = lds[t];
    if (t >= off) val += lds[t - off];
    __syncthreads();
    lds[t] = val;
    __syncthreads();
  }
  int ex = lds[t] - sum;
  if (base + 0 < n) exc[base + 0] = ex;
  ex += v0;
  if (base + 1 < n) exc[base + 1] = ex;
  ex += v1;
  if (base + 2 < n) exc[base + 2] = ex;
  ex += v2;
  if (base + 3 < n) exc[base + 3] = ex;
  if (t == 255) bsum[blockIdx.x] = lds[255];
}

__global__ __launch_bounds__(128) void k_scan2(int* __restrict__ bsum, int nb) {
  __shared__ int lds[128];
  int t = threadIdx.x;
  int v = (t < nb) ? bsum[t] : 0;
  lds[t] = v;
  __syncthreads();
  for (int off = 1; off < 128; off <<= 1) {
    int val = lds[t];
    if (t >= off) val += lds[t - off];
    __syncthreads();
    lds[t] = val;
    __syncthreads();
  }
  if (t < nb) bsum[t] = lds[t] - v;
}

__global__ __launch_bounds__(256) void k_scan3(int* __restrict__ exc,
                                               const int* __restrict__ bsum, int n) {
  int i = blockIdx.x * blockDim.x + threadIdx.x;
  if (i < n) exc[i] += bsum[i >> 10];
}

__global__ __launch_bounds__(256) void k_fill(const int* __restrict__ src,
                                              const int* __restrict__ dst,
                                              const int* __restrict__ rowStart,
                                              int* __restrict__ fillPos,
                                              int* __restrict__ eSrc, int E) {
  int i = blockIdx.x * blockDim.x + threadIdx.x;
  int stride = gridDim.x * blockDim.x;
  for (; i < E; i += stride) {
    int d = dst[i];
    int p = rowStart[d] + atomicAdd(&fillPos[d], 1);
    eSrc[p] = src[i];
  }
}

// ------------------------- fast path: bf16 gather --------------------------

// s[row] = bf16(dinv[row] * h[row]); s packed as uint words (2 cols/word).
// One thread per uint4 (8 cols).
__global__ __launch_bounds__(256) void k_scale(const float* __restrict__ h,
                                               const float* __restrict__ dinv,
                                               uint4* __restrict__ s4, int nQuads) {
  int i = blockIdx.x * blockDim.x + threadIdx.x;
  int stride = gridDim.x * blockDim.x;
  for (; i < nQuads; i += stride) {
    int row = i >> 4;          // 16 uint4 per 128-col row
    int q = i & 15;            // cols 8q..8q+7
    float dv = dinv[row];
    const float4* hp = (const float4*)&h[(size_t)row * 128 + 8 * q];
    float4 a = hp[0], b = hp[1];
    uint4 o;
    o.x = (unsigned)f2bf(dv * a.x) | ((unsigned)f2bf(dv * a.y) << 16);
    o.y = (unsigned)f2bf(dv * a.z) | ((unsigned)f2bf(dv * a.w) << 16);
    o.z = (unsigned)f2bf(dv * b.x) | ((unsigned)f2bf(dv * b.y) << 16);
    o.w = (unsigned)f2bf(dv * b.z) | ((unsigned)f2bf(dv * b.w) << 16);
    s4[i] = o;
  }
}

// Fused layer, bf16 gather source. Per wave-owned node d:
//   t = dinv[d] * ( sum_{src->d} s[src] + s[d] )      [128] (s = dinv*h in bf16)
//   out[d] = maybe_relu( t @ W + b )                  [NFO]
// Lane owns cols {2l,2l+1} (one uint of s). 512 thr = 8 waves share LDS W.
template <int NFO, bool RELU>
__global__ __launch_bounds__(512) void k_layer_bf(const unsigned* __restrict__ sU,
                                                  const float* __restrict__ W,
                                                  const float* __restrict__ bias,
                                                  const float* __restrict__ dinv,
                                                  const int* __restrict__ eSrc,
                                                  const int* __restrict__ rowStart,
                                                  const int* __restrict__ cnt,
                                                  float* __restrict__ out, int n) {
  __shared__ float Wl[128 * NFO];
  for (int t = threadIdx.x; t < 128 * NFO; t += 512) Wl[t] = W[t];
  __syncthreads();
  const int wid = threadIdx.x >> 6, lane = threadIdx.x & 63;
  for (int node = blockIdx.x * 8 + wid; node < n; node += gridDim.x * 8) {
    const int st = rowStart[node], c = cnt[node];
    const int* es = eSrc + st;
    const float dv = dinv[node];
    unsigned vs = sU[(size_t)node * 64 + lane];      // self term (s[d])
    float ax = bfLo(vs), ay = bfHi(vs);
    const int cl = c < 64 ? c : 64;
    int myIdx = (lane < cl) ? es[lane] : 0;          // indices: 1 load / 64 edges
    int j = 0;
    for (; j + 8 <= cl; j += 8) {
      int i0 = __shfl(myIdx, j + 0), i1 = __shfl(myIdx, j + 1);
      int i2 = __shfl(myIdx, j + 2), i3 = __shfl(myIdx, j + 3);
      int i4 = __shfl(myIdx, j + 4), i5 = __shfl(myIdx, j + 5);
      int i6 = __shfl(myIdx, j + 6), i7 = __shfl(myIdx, j + 7);
      unsigned v0 = sU[(size_t)i0 * 64 + lane], v1 = sU[(size_t)i1 * 64 + lane];
      unsigned v2 = sU[(size_t)i2 * 64 + lane], v3 = sU[(size_t)i3 * 64 + lane];
      unsigned v4 = sU[(size_t)i4 * 64 + lane], v5 = sU[(size_t)i5 * 64 + lane];
      unsigned v6 = sU[(size_t)i6 * 64 + lane], v7 = sU[(size_t)i7 * 64 + lane];
      ax += bfLo(v0); ay += bfHi(v0);
      ax += bfLo(v1); ay += bfHi(v1);
      ax += bfLo(v2); ay += bfHi(v2);
      ax += bfLo(v3); ay += bfHi(v3);
      ax += bfLo(v4); ay += bfHi(v4);
      ax += bfLo(v5); ay += bfHi(v5);
      ax += bfLo(v6); ay += bfHi(v6);
      ax += bfLo(v7); ay += bfHi(v7);
    }
    for (; j < cl; j++) {
      int i0 = __shfl(myIdx, j);
      unsigned v = sU[(size_t)i0 * 64 + lane];
      ax += bfLo(v); ay += bfHi(v);
    }
    for (; j < c; j++) {                              // (c > 64 tail, ~never)
      unsigned v = sU[(size_t)es[j] * 64 + lane];
      ax += bfLo(v); ay += bfHi(v);
    }
    ax *= dv; ay *= dv;                               // t[2l], t[2l+1]
    if constexpr (NFO == 128) {
      float o0 = 0.f, o1 = 0.f;
      #pragma unroll
      for (int kk = 0; kk < 64; kk++) {
        float xa = __shfl(ax, kk);
        float xb = __shfl(ay, kk);
        float2 wA = *(const float2*)&Wl[(2 * kk) * 128 + 2 * lane];
        float2 wB = *(const float2*)&Wl[(2 * kk + 1) * 128 + 2 * lane];
        o0 = fmaf(xa, wA.x, o0); o1 = fmaf(xa, wA.y, o1);
        o0 = fmaf(xb, wB.x, o0); o1 = fmaf(xb, wB.y, o1);
      }
      float2 bb = *(const float2*)&bias[2 * lane];
      float r0 = o0 + bb.x, r1 = o1 + bb.y;
      if (RELU) { r0 = fmaxf(r0, 0.f); r1 = fmaxf(r1, 0.f); }
      *(float2*)&out[(size_t)node * 128 + 2 * lane] = make_float2(r0, r1);
    } else {
      float o0 = 0.f;
      #pragma unroll
      for (int kk = 0; kk < 64; kk++) {
        float xa = __shfl(ax, kk);
        float xb = __shfl(ay, kk);
        o0 = fmaf(xa, Wl[(2 * kk) * NFO + lane], o0);
        o0 = fmaf(xb, Wl[(2 * kk + 1) * NFO + lane], o0);
      }
      float r0 = o0 + bias[lane];
      if (RELU) r0 = fmaxf(r0, 0.f);
      out[(size_t)node * NFO + lane] = r0;
    }
  }
}

// --------------------- fallback path: round-4 fp32 fused -------------------

template <int NFO, bool RELU>
__global__ __launch_bounds__(512) void k_layer_f32(const float* __restrict__ in,
                                                   const float* __restrict__ W,
                                                   const float* __restrict__ bias,
                                                   const float* __restrict__ dinv,
                                                   const int* __restrict__ eSrc,
                                                   const int* __restrict__ rowStart,
                                                   const int* __restrict__ cnt,
                                                   float* __restrict__ out, int n) {
  __shared__ float Wl[128 * NFO];
  for (int t = threadIdx.x; t < 128 * NFO; t += 512) Wl[t] = W[t];
  __syncthreads();
  const int wid = threadIdx.x >> 6, lane = threadIdx.x & 63;
  for (int node = blockIdx.x * 8 + wid; node < n; node += gridDim.x * 8) {
    const int s = rowStart[node], c = cnt[node];
    const int* es = eSrc + s;
    const float dv = dinv[node];
    float2 x2 = *(const float2*)&in[(size_t)node * 128 + 2 * lane];
    float ax = dv * x2.x, ay = dv * x2.y;
    int j = 0;
    for (; j + 4 <= c; j += 4) {
      int s0 = es[j], s1 = es[j + 1], s2 = es[j + 2], s3 = es[j + 3];
      float d0 = dinv[s0], d1 = dinv[s1], d2 = dinv[s2], d3 = dinv[s3];
      float2 v0 = *(const float2*)&in[(size_t)s0 * 128 + 2 * lane];
      float2 v1 = *(const float2*)&in[(size_t)s1 * 128 + 2 * lane];
      float2 v2 = *(const float2*)&in[(size_t)s2 * 128 + 2 * lane];
      float2 v3 = *(const float2*)&in[(size_t)s3 * 128 + 2 * lane];
      ax = fmaf(d0, v0.x, ax); ay = fmaf(d0, v0.y, ay);
      ax = fmaf(d1, v1.x, ax); ay = fmaf(d1, v1.y, ay);
      ax = fmaf(d2, v2.x, ax); ay = fmaf(d2, v2.y, ay);
      ax = fmaf(d3, v3.x, ax); ay = fmaf(d3, v3.y, ay);
    }
    for (; j < c; j++) {
      int sj = es[j];
      float dj = dinv[sj];
      float2 v = *(const float2*)&in[(size_t)sj * 128 + 2 * lane];
      ax = fmaf(dj, v.x, ax); ay = fmaf(dj, v.y, ay);
    }
    ax *= dv; ay *= dv;
    if constexpr (NFO == 128) {
      float o0 = 0.f, o1 = 0.f;
      #pragma unroll
      for (int kk = 0; kk < 64; kk++) {
        float xa = __shfl(ax, kk);
        float xb = __shfl(ay, kk);
        float2 wA = *(const float2*)&Wl[(2 * kk) * 128 + 2 * lane];
        float2 wB = *(const float2*)&Wl[(2 * kk + 1) * 128 + 2 * lane];
        o0 = fmaf(xa, wA.x, o0); o1 = fmaf(xa, wA.y, o1);
        o0 = fmaf(xb, wB.x, o0); o1 = fmaf(xb, wB.y, o1);
      }
      float2 bb = *(const float2*)&bias[2 * lane];
      float r0 = o0 + bb.x, r1 = o1 + bb.y;
      if (RELU) { r0 = fmaxf(r0, 0.f); r1 = fmaxf(r1, 0.f); }
      *(float2*)&out[(size_t)node * 128 + 2 * lane] = make_float2(r0, r1);
    } else {
      float o0 = 0.f;
      #pragma unroll
      for (int kk = 0; kk < 64; kk++) {
        float xa = __shfl(ax, kk);
        float xb = __shfl(ay, kk);
        o0 = fmaf(xa, Wl[(2 * kk) * NFO + lane], o0);
        o0 = fmaf(xb, Wl[(2 * kk + 1) * NFO + lane], o0);
      }
      float r0 = o0 + bias[lane];
      if (RELU) r0 = fmaxf(r0, 0.f);
      out[(size_t)node * NFO + lane] = r0;
    }
  }
}

// ---------------------------------------------------------------------------

extern "C" void kernel_launch(void* const* d_in, const int* in_sizes, int n_in,
                              void* d_out, int out_size, void* d_ws, size_t ws_size,
                              hipStream_t stream) {
  const float* x  = (const float*)d_in[0];
  const int*   ei = (const int*)d_in[1];
  const float* W1 = (const float*)d_in[2];
  const float* b1 = (const float*)d_in[3];
  const float* W2 = (const float*)d_in[4];
  const float* b2 = (const float*)d_in[5];
  const float* W3 = (const float*)d_in[6];
  const float* b3 = (const float*)d_in[7];

  const int N = in_sizes[0] / 128;
  const int E = in_sizes[1] / 2;
  const int* src = ei;
  const int* dst = ei + E;

  char* ws = (char*)d_ws;
  size_t off = 0;
  auto alloc = [&](size_t bytes) -> void* {
    void* p = ws + off;
    off = (off + bytes + 255) & ~(size_t)255;
    return p;
  };
  int*   cnt      = (int*)alloc((size_t)N * 4);
  int*   fillPos  = (int*)alloc((size_t)N * 4);
  int*   rowStart = (int*)alloc((size_t)N * 4);
  float* dinv     = (float*)alloc((size_t)N * 4);
  int*   bsum     = (int*)alloc(512);
  int*   eSrc     = (int*)alloc((size_t)E * 4);
  size_t csrBytes = off;
  unsigned* sU    = (unsigned*)alloc((size_t)N * 64 * 4);  // bf16 rows, 256B each
  const bool fast = (ws_size >= off);                       // ~33.7 MB needed

  float* y    = (float*)d_out;          // [N,64]
  float* out1 = y + (size_t)N * 64;     // [N,128]
  float* out2 = out1 + (size_t)N * 128; // [N,128]

  // ---- CSR build (re-derived from inputs every call) ----
  k_zero<<<(N + 255) / 256, 256, 0, stream>>>(cnt, fillPos, N);
  k_deg<<<2048, 256, 0, stream>>>(dst, cnt, E);
  k_dinv<<<(N + 255) / 256, 256, 0, stream>>>(cnt, dinv, N);
  int nChunks = (N + 1023) / 1024;
  k_scan1<<<nChunks, 256, 0, stream>>>(cnt, rowStart, bsum, N);
  k_scan2<<<1, 128, 0, stream>>>(bsum, nChunks);
  k_scan3<<<(N + 255) / 256, 256, 0, stream>>>(rowStart, bsum, N);
  k_fill<<<2048, 256, 0, stream>>>(src, dst, rowStart, fillPos, eSrc, E);

  if (fast) {
    const int nQuads = N * 16;
    const int sBlocks = (nQuads + 255) / 256;
    k_scale<<<sBlocks, 256, 0, stream>>>(x, dinv, (uint4*)sU, nQuads);
    k_layer_bf<128, true ><<<1024, 512, 0, stream>>>(sU, W1, b1, dinv, eSrc, rowStart, cnt, out1, N);
    k_scale<<<sBlocks, 256, 0, stream>>>(out1, dinv, (uint4*)sU, nQuads);
    k_layer_bf<128, true ><<<1024, 512, 0, stream>>>(sU, W2, b2, dinv, eSrc, rowStart, cnt, out2, N);
    k_scale<<<sBlocks, 256, 0, stream>>>(out2, dinv, (uint4*)sU, nQuads);
    k_layer_bf<64,  false><<<1024, 512, 0, stream>>>(sU, W3, b3, dinv, eSrc, rowStart, cnt, y,    N);
  } else {
    (void)csrBytes;
    k_layer_f32<128, true ><<<1024, 512, 0, stream>>>(x,    W1, b1, dinv, eSrc, rowStart, cnt, out1, N);
    k_layer_f32<128, true ><<<1024, 512, 0, stream>>>(out1, W2, b2, dinv, eSrc, rowStart, cnt, out2, N);
    k_layer_f32<64,  false><<<1024, 512, 0, stream>>>(out2, W3, b3, dinv, eSrc, rowStart, cnt, y,    N);
  }
}

// Round 7
// 1455.387 us; speedup vs baseline: 1.9212x; 1.9212x over previous
//
#include <hip/hip_runtime.h>
#include <math.h>

// ---------------------------------------------------------------------------
// 3-layer GCN on MI355X, fused aggregate-then-GEMM form.
//   out = relu( (A_hat @ in) @ W + b ),  A_hat = D^-1/2 (A+I) D^-1/2
// Round-7 A/B experiment:
//   L1: fp32 gather kernel (round-4 anchor: 553us, FETCH 769MB)
//   L2: bf16 rows gathered as uint2 (8B/lane): two 32-lane halves fetch TWO
//       edges per instruction -> every quarter-wave request is 128B again.
//       (Round-6 dword/4B-lane gathers over-fetched 3.6x: 64B requests.)
//   L3: fp32 gather kernel.
// CSR over dst rebuilt on-device every call.
// ---------------------------------------------------------------------------

__device__ __forceinline__ unsigned short f2bf(float f) {
  unsigned u = __float_as_uint(f);
  return (unsigned short)((u + 0x7FFFu + ((u >> 16) & 1u)) >> 16);
}
__device__ __forceinline__ float bfLo(unsigned v) { return __uint_as_float(v << 16); }
__device__ __forceinline__ float bfHi(unsigned v) { return __uint_as_float(v & 0xFFFF0000u); }

// ------------------------------- CSR build ---------------------------------

__global__ __launch_bounds__(256) void k_zero(int* __restrict__ cnt,
                                              int* __restrict__ fillPos, int n) {
  int i = blockIdx.x * blockDim.x + threadIdx.x;
  if (i < n) { cnt[i] = 0; fillPos[i] = 0; }
}

__global__ __launch_bounds__(256) void k_deg(const int* __restrict__ dst,
                                             int* __restrict__ cnt, int E) {
  int i = blockIdx.x * blockDim.x + threadIdx.x;
  int stride = gridDim.x * blockDim.x;
  for (; i < E; i += stride) atomicAdd(&cnt[dst[i]], 1);
}

__global__ __launch_bounds__(256) void k_dinv(const int* __restrict__ cnt,
                                              float* __restrict__ dinv, int n) {
  int i = blockIdx.x * blockDim.x + threadIdx.x;
  if (i < n) dinv[i] = rsqrtf(1.0f + (float)cnt[i]);
}

__global__ __launch_bounds__(256) void k_scan1(const int* __restrict__ cnt,
                                               int* __restrict__ exc,
                                               int* __restrict__ bsum, int n) {
  __shared__ int lds[256];
  int t = threadIdx.x;
  int base = blockIdx.x * 1024 + t * 4;
  int v0 = (base + 0 < n) ? cnt[base + 0] : 0;
  int v1 = (base + 1 < n) ? cnt[base + 1] : 0;
  int v2 = (base + 2 < n) ? cnt[base + 2] : 0;
  int v3 = (base + 3 < n) ? cnt[base + 3] : 0;
  int sum = v0 + v1 + v2 + v3;
  lds[t] = sum;
  __syncthreads();
  for (int off = 1; off < 256; off <<= 1) {
    int val = lds[t];
    if (t >= off) val += lds[t - off];
    __syncthreads();
    lds[t] = val;
    __syncthreads();
  }
  int ex = lds[t] - sum;
  if (base + 0 < n) exc[base + 0] = ex;
  ex += v0;
  if (base + 1 < n) exc[base + 1] = ex;
  ex += v1;
  if (base + 2 < n) exc[base + 2] = ex;
  ex += v2;
  if (base + 3 < n) exc[base + 3] = ex;
  if (t == 255) bsum[blockIdx.x] = lds[255];
}

__global__ __launch_bounds__(128) void k_scan2(int* __restrict__ bsum, int nb) {
  __shared__ int lds[128];
  int t = threadIdx.x;
  int v = (t < nb) ? bsum[t] : 0;
  lds[t] = v;
  __syncthreads();
  for (int off = 1; off < 128; off <<= 1) {
    int val = lds[t];
    if (t >= off) val += lds[t - off];
    __syncthreads();
    lds[t] = val;
    __syncthreads();
  }
  if (t < nb) bsum[t] = lds[t] - v;
}

__global__ __launch_bounds__(256) void k_scan3(int* __restrict__ exc,
                                               const int* __restrict__ bsum, int n) {
  int i = blockIdx.x * blockDim.x + threadIdx.x;
  if (i < n) exc[i] += bsum[i >> 10];
}

__global__ __launch_bounds__(256) void k_fill(const int* __restrict__ src,
                                              const int* __restrict__ dst,
                                              const int* __restrict__ rowStart,
                                              int* __restrict__ fillPos,
                                              int* __restrict__ eSrc, int E) {
  int i = blockIdx.x * blockDim.x + threadIdx.x;
  int stride = gridDim.x * blockDim.x;
  for (; i < E; i += stride) {
    int d = dst[i];
    int p = rowStart[d] + atomicAdd(&fillPos[d], 1);
    eSrc[p] = src[i];
  }
}

// ---------------- bf16 prescale: s = bf16(dinv * h), 256B rows -------------

__global__ __launch_bounds__(256) void k_scale(const float* __restrict__ h,
                                               const float* __restrict__ dinv,
                                               uint4* __restrict__ s4, int nQuads) {
  int i = blockIdx.x * blockDim.x + threadIdx.x;
  int stride = gridDim.x * blockDim.x;
  for (; i < nQuads; i += stride) {
    int row = i >> 4;
    int q = i & 15;
    float dv = dinv[row];
    const float4* hp = (const float4*)&h[(size_t)row * 128 + 8 * q];
    float4 a = hp[0], b = hp[1];
    uint4 o;
    o.x = (unsigned)f2bf(dv * a.x) | ((unsigned)f2bf(dv * a.y) << 16);
    o.y = (unsigned)f2bf(dv * a.z) | ((unsigned)f2bf(dv * a.w) << 16);
    o.z = (unsigned)f2bf(dv * b.x) | ((unsigned)f2bf(dv * b.y) << 16);
    o.w = (unsigned)f2bf(dv * b.z) | ((unsigned)f2bf(dv * b.w) << 16);
    s4[i] = o;
  }
}

// ------------- L2 kernel: 2 edges per wave instruction, uint2/lane ---------
// Lane l: half = l>>5, sl = l&31. Lane owns bf16 cols 4*sl..4*sl+3.
// Per pair step: half 0 gathers edge A's row, half 1 edge B's row (8B/lane,
// each 32-lane half = 256B contiguous -> quarter-wave requests are 128B).
// Cross-half sum via shfl_xor(32) at the end.
__global__ __launch_bounds__(512) void k_layer_bf2(const unsigned* __restrict__ sU,
                                                   const float* __restrict__ W,
                                                   const float* __restrict__ bias,
                                                   const float* __restrict__ dinv,
                                                   const int* __restrict__ eSrc,
                                                   const int* __restrict__ rowStart,
                                                   const int* __restrict__ cnt,
                                                   float* __restrict__ out, int n) {
  __shared__ float Wl[128 * 128];
  for (int t = threadIdx.x; t < 128 * 128; t += 512) Wl[t] = W[t];
  __syncthreads();
  const int wid = threadIdx.x >> 6, lane = threadIdx.x & 63;
  const int half = lane >> 5, sl = lane & 31;
  for (int node = blockIdx.x * 8 + wid; node < n; node += gridDim.x * 8) {
    const int st = rowStart[node], c = cnt[node];
    const int* es = eSrc + st;
    const float dv = dinv[node];
    uint2 vs = *(const uint2*)&sU[(size_t)node * 64 + 2 * sl];  // self row
    float a0, a1, a2, a3;
    if (half == 0) {
      a0 = bfLo(vs.x); a1 = bfHi(vs.x); a2 = bfLo(vs.y); a3 = bfHi(vs.y);
    } else {
      a0 = a1 = a2 = a3 = 0.f;
    }
    const int cl = c < 64 ? c : 64;
    int myIdx = (lane < cl) ? es[lane] : 0;
    int j = 0;
    for (; j + 8 <= cl; j += 8) {  // 4 pairs = 8 edges, loads independent
      int iA0 = __shfl(myIdx, j + 0), iB0 = __shfl(myIdx, j + 1);
      int iA1 = __shfl(myIdx, j + 2), iB1 = __shfl(myIdx, j + 3);
      int iA2 = __shfl(myIdx, j + 4), iB2 = __shfl(myIdx, j + 5);
      int iA3 = __shfl(myIdx, j + 6), iB3 = __shfl(myIdx, j + 7);
      int x0 = half ? iB0 : iA0;
      int x1 = half ? iB1 : iA1;
      int x2 = half ? iB2 : iA2;
      int x3 = half ? iB3 : iA3;
      uint2 v0 = *(const uint2*)&sU[(size_t)x0 * 64 + 2 * sl];
      uint2 v1 = *(const uint2*)&sU[(size_t)x1 * 64 + 2 * sl];
      uint2 v2 = *(const uint2*)&sU[(size_t)x2 * 64 + 2 * sl];
      uint2 v3 = *(const uint2*)&sU[(size_t)x3 * 64 + 2 * sl];
      a0 += bfLo(v0.x); a1 += bfHi(v0.x); a2 += bfLo(v0.y); a3 += bfHi(v0.y);
      a0 += bfLo(v1.x); a1 += bfHi(v1.x); a2 += bfLo(v1.y); a3 += bfHi(v1.y);
      a0 += bfLo(v2.x); a1 += bfHi(v2.x); a2 += bfLo(v2.y); a3 += bfHi(v2.y);
      a0 += bfLo(v3.x); a1 += bfHi(v3.x); a2 += bfLo(v3.y); a3 += bfHi(v3.y);
    }
    for (; j < c; j += 2) {  // pair tail (handles odd c and c>64)
      int iA = (j < cl) ? __shfl(myIdx, j) : es[j];
      int hasB = (j + 1 < c);
      int iB = hasB ? ((j + 1 < cl) ? __shfl(myIdx, j + 1) : es[j + 1]) : iA;
      int x = half ? iB : iA;
      uint2 v = *(const uint2*)&sU[(size_t)x * 64 + 2 * sl];
      if (half && !hasB) { v.x = 0u; v.y = 0u; }
      a0 += bfLo(v.x); a1 += bfHi(v.x); a2 += bfLo(v.y); a3 += bfHi(v.y);
    }
    // combine halves: both end up with the full sum
    a0 += __shfl_xor(a0, 32);
    a1 += __shfl_xor(a1, 32);
    a2 += __shfl_xor(a2, 32);
    a3 += __shfl_xor(a3, 32);
    a0 *= dv; a1 *= dv; a2 *= dv; a3 *= dv;  // t[4*sl + r]
    // row-GEMM: out_col = sum_k t[k] * W[k][col]; t[4q+r] from lane q (a_r)
    float o0 = 0.f, o1 = 0.f;
    #pragma unroll
    for (int q = 0; q < 32; q++) {
      float t0 = __shfl(a0, q);
      float t1 = __shfl(a1, q);
      float t2 = __shfl(a2, q);
      float t3 = __shfl(a3, q);
      float2 w0 = *(const float2*)&Wl[(4 * q + 0) * 128 + 2 * lane];
      float2 w1 = *(const float2*)&Wl[(4 * q + 1) * 128 + 2 * lane];
      float2 w2 = *(const float2*)&Wl[(4 * q + 2) * 128 + 2 * lane];
      float2 w3 = *(const float2*)&Wl[(4 * q + 3) * 128 + 2 * lane];
      o0 = fmaf(t0, w0.x, o0); o1 = fmaf(t0, w0.y, o1);
      o0 = fmaf(t1, w1.x, o0); o1 = fmaf(t1, w1.y, o1);
      o0 = fmaf(t2, w2.x, o0); o1 = fmaf(t2, w2.y, o1);
      o0 = fmaf(t3, w3.x, o0); o1 = fmaf(t3, w3.y, o1);
    }
    float2 bb = *(const float2*)&bias[2 * lane];
    float r0 = fmaxf(o0 + bb.x, 0.f), r1 = fmaxf(o1 + bb.y, 0.f);
    *(float2*)&out[(size_t)node * 128 + 2 * lane] = make_float2(r0, r1);
  }
}

// --------------------- fp32 fused kernel (round-4 anchor) ------------------

template <int NFO, bool RELU>
__global__ __launch_bounds__(512) void k_layer_f32(const float* __restrict__ in,
                                                   const float* __restrict__ W,
                                                   const float* __restrict__ bias,
                                                   const float* __restrict__ dinv,
                                                   const int* __restrict__ eSrc,
                                                   const int* __restrict__ rowStart,
                                                   const int* __restrict__ cnt,
                                                   float* __restrict__ out, int n) {
  __shared__ float Wl[128 * NFO];
  for (int t = threadIdx.x; t < 128 * NFO; t += 512) Wl[t] = W[t];
  __syncthreads();
  const int wid = threadIdx.x >> 6, lane = threadIdx.x & 63;
  for (int node = blockIdx.x * 8 + wid; node < n; node += gridDim.x * 8) {
    const int s = rowStart[node], c = cnt[node];
    const int* es = eSrc + s;
    const float dv = dinv[node];
    float2 x2 = *(const float2*)&in[(size_t)node * 128 + 2 * lane];
    float ax = dv * x2.x, ay = dv * x2.y;
    int j = 0;
    for (; j + 4 <= c; j += 4) {
      int s0 = es[j], s1 = es[j + 1], s2 = es[j + 2], s3 = es[j + 3];
      float d0 = dinv[s0], d1 = dinv[s1], d2 = dinv[s2], d3 = dinv[s3];
      float2 v0 = *(const float2*)&in[(size_t)s0 * 128 + 2 * lane];
      float2 v1 = *(const float2*)&in[(size_t)s1 * 128 + 2 * lane];
      float2 v2 = *(const float2*)&in[(size_t)s2 * 128 + 2 * lane];
      float2 v3 = *(const float2*)&in[(size_t)s3 * 128 + 2 * lane];
      ax = fmaf(d0, v0.x, ax); ay = fmaf(d0, v0.y, ay);
      ax = fmaf(d1, v1.x, ax); ay = fmaf(d1, v1.y, ay);
      ax = fmaf(d2, v2.x, ax); ay = fmaf(d2, v2.y, ay);
      ax = fmaf(d3, v3.x, ax); ay = fmaf(d3, v3.y, ay);
    }
    for (; j < c; j++) {
      int sj = es[j];
      float dj = dinv[sj];
      float2 v = *(const float2*)&in[(size_t)sj * 128 + 2 * lane];
      ax = fmaf(dj, v.x, ax); ay = fmaf(dj, v.y, ay);
    }
    ax *= dv; ay *= dv;
    if constexpr (NFO == 128) {
      float o0 = 0.f, o1 = 0.f;
      #pragma unroll
      for (int kk = 0; kk < 64; kk++) {
        float xa = __shfl(ax, kk);
        float xb = __shfl(ay, kk);
        float2 wA = *(const float2*)&Wl[(2 * kk) * 128 + 2 * lane];
        float2 wB = *(const float2*)&Wl[(2 * kk + 1) * 128 + 2 * lane];
        o0 = fmaf(xa, wA.x, o0); o1 = fmaf(xa, wA.y, o1);
        o0 = fmaf(xb, wB.x, o0); o1 = fmaf(xb, wB.y, o1);
      }
      float2 bb = *(const float2*)&bias[2 * lane];
      float r0 = o0 + bb.x, r1 = o1 + bb.y;
      if (RELU) { r0 = fmaxf(r0, 0.f); r1 = fmaxf(r1, 0.f); }
      *(float2*)&out[(size_t)node * 128 + 2 * lane] = make_float2(r0, r1);
    } else {
      float o0 = 0.f;
      #pragma unroll
      for (int kk = 0; kk < 64; kk++) {
        float xa = __shfl(ax, kk);
        float xb = __shfl(ay, kk);
        o0 = fmaf(xa, Wl[(2 * kk) * NFO + lane], o0);
        o0 = fmaf(xb, Wl[(2 * kk + 1) * NFO + lane], o0);
      }
      float r0 = o0 + bias[lane];
      if (RELU) r0 = fmaxf(r0, 0.f);
      out[(size_t)node * NFO + lane] = r0;
    }
  }
}

// ---------------------------------------------------------------------------

extern "C" void kernel_launch(void* const* d_in, const int* in_sizes, int n_in,
                              void* d_out, int out_size, void* d_ws, size_t ws_size,
                              hipStream_t stream) {
  const float* x  = (const float*)d_in[0];
  const int*   ei = (const int*)d_in[1];
  const float* W1 = (const float*)d_in[2];
  const float* b1 = (const float*)d_in[3];
  const float* W2 = (const float*)d_in[4];
  const float* b2 = (const float*)d_in[5];
  const float* W3 = (const float*)d_in[6];
  const float* b3 = (const float*)d_in[7];

  const int N = in_sizes[0] / 128;
  const int E = in_sizes[1] / 2;
  const int* src = ei;
  const int* dst = ei + E;

  char* ws = (char*)d_ws;
  size_t off = 0;
  auto alloc = [&](size_t bytes) -> void* {
    void* p = ws + off;
    off = (off + bytes + 255) & ~(size_t)255;
    return p;
  };
  int*   cnt      = (int*)alloc((size_t)N * 4);
  int*   fillPos  = (int*)alloc((size_t)N * 4);
  int*   rowStart = (int*)alloc((size_t)N * 4);
  float* dinv     = (float*)alloc((size_t)N * 4);
  int*   bsum     = (int*)alloc(512);
  int*   eSrc     = (int*)alloc((size_t)E * 4);
  unsigned* sU    = (unsigned*)alloc((size_t)N * 64 * 4);  // bf16 rows, 256B
  const bool fast = (ws_size >= off);                       // ~33.7 MB

  float* y    = (float*)d_out;          // [N,64]
  float* out1 = y + (size_t)N * 64;     // [N,128]
  float* out2 = out1 + (size_t)N * 128; // [N,128]

  // ---- CSR build ----
  k_zero<<<(N + 255) / 256, 256, 0, stream>>>(cnt, fillPos, N);
  k_deg<<<2048, 256, 0, stream>>>(dst, cnt, E);
  k_dinv<<<(N + 255) / 256, 256, 0, stream>>>(cnt, dinv, N);
  int nChunks = (N + 1023) / 1024;
  k_scan1<<<nChunks, 256, 0, stream>>>(cnt, rowStart, bsum, N);
  k_scan2<<<1, 128, 0, stream>>>(bsum, nChunks);
  k_scan3<<<(N + 255) / 256, 256, 0, stream>>>(rowStart, bsum, N);
  k_fill<<<2048, 256, 0, stream>>>(src, dst, rowStart, fillPos, eSrc, E);

  // ---- layers ----
  // L1: fp32 anchor
  k_layer_f32<128, true><<<1024, 512, 0, stream>>>(x, W1, b1, dinv, eSrc, rowStart, cnt, out1, N);
  if (fast) {
    // L2: bf16 2-edges-per-instruction experiment
    const int nQuads = N * 16;
    k_scale<<<(nQuads + 255) / 256, 256, 0, stream>>>(out1, dinv, (uint4*)sU, nQuads);
    k_layer_bf2<<<1024, 512, 0, stream>>>(sU, W2, b2, dinv, eSrc, rowStart, cnt, out2, N);
  } else {
    k_layer_f32<128, true><<<1024, 512, 0, stream>>>(out1, W2, b2, dinv, eSrc, rowStart, cnt, out2, N);
  }
  // L3: fp32
  k_layer_f32<64, false><<<1024, 512, 0, stream>>>(out2, W3, b3, dinv, eSrc, rowStart, cnt, y, N);
}

// Round 8
// 1368.959 us; speedup vs baseline: 2.0425x; 1.0631x over previous
//
#include <hip/hip_runtime.h>
#include <math.h>

// ---------------------------------------------------------------------------
// 3-layer GCN on MI355X, fused aggregate-then-GEMM form.
//   out = relu( (A_hat @ in) @ W + b ),  A_hat = D^-1/2 (A+I) D^-1/2
// All layers: bf16 prescaled gather rows (s = bf16(dinv*h), 256B/row),
// gathered 8B/lane with two 32-lane halves fetching TWO edges per VMEM
// instruction (keeps every quarter-wave request 128B contiguous -> no fetch
// amplification; round-6's 4B/lane had 3.6x amplification).
// Warm-time evidence (round 7): bf2 layer ~290-340us vs fp32 553us.
// CSR over dst rebuilt on-device every call.
// ---------------------------------------------------------------------------

__device__ __forceinline__ unsigned short f2bf(float f) {
  unsigned u = __float_as_uint(f);
  return (unsigned short)((u + 0x7FFFu + ((u >> 16) & 1u)) >> 16);
}
__device__ __forceinline__ float bfLo(unsigned v) { return __uint_as_float(v << 16); }
__device__ __forceinline__ float bfHi(unsigned v) { return __uint_as_float(v & 0xFFFF0000u); }

// ------------------------------- CSR build ---------------------------------

__global__ __launch_bounds__(256) void k_zero(int* __restrict__ cnt,
                                              int* __restrict__ fillPos, int n) {
  int i = blockIdx.x * blockDim.x + threadIdx.x;
  if (i < n) { cnt[i] = 0; fillPos[i] = 0; }
}

__global__ __launch_bounds__(256) void k_deg(const int* __restrict__ dst,
                                             int* __restrict__ cnt, int E) {
  int i = blockIdx.x * blockDim.x + threadIdx.x;
  int stride = gridDim.x * blockDim.x;
  for (; i < E; i += stride) atomicAdd(&cnt[dst[i]], 1);
}

__global__ __launch_bounds__(256) void k_dinv(const int* __restrict__ cnt,
                                              float* __restrict__ dinv, int n) {
  int i = blockIdx.x * blockDim.x + threadIdx.x;
  if (i < n) dinv[i] = rsqrtf(1.0f + (float)cnt[i]);
}

__global__ __launch_bounds__(256) void k_scan1(const int* __restrict__ cnt,
                                               int* __restrict__ exc,
                                               int* __restrict__ bsum, int n) {
  __shared__ int lds[256];
  int t = threadIdx.x;
  int base = blockIdx.x * 1024 + t * 4;
  int v0 = (base + 0 < n) ? cnt[base + 0] : 0;
  int v1 = (base + 1 < n) ? cnt[base + 1] : 0;
  int v2 = (base + 2 < n) ? cnt[base + 2] : 0;
  int v3 = (base + 3 < n) ? cnt[base + 3] : 0;
  int sum = v0 + v1 + v2 + v3;
  lds[t] = sum;
  __syncthreads();
  for (int off = 1; off < 256; off <<= 1) {
    int val = lds[t];
    if (t >= off) val += lds[t - off];
    __syncthreads();
    lds[t] = val;
    __syncthreads();
  }
  int ex = lds[t] - sum;
  if (base + 0 < n) exc[base + 0] = ex;
  ex += v0;
  if (base + 1 < n) exc[base + 1] = ex;
  ex += v1;
  if (base + 2 < n) exc[base + 2] = ex;
  ex += v2;
  if (base + 3 < n) exc[base + 3] = ex;
  if (t == 255) bsum[blockIdx.x] = lds[255];
}

__global__ __launch_bounds__(128) void k_scan2(int* __restrict__ bsum, int nb) {
  __shared__ int lds[128];
  int t = threadIdx.x;
  int v = (t < nb) ? bsum[t] : 0;
  lds[t] = v;
  __syncthreads();
  for (int off = 1; off < 128; off <<= 1) {
    int val = lds[t];
    if (t >= off) val += lds[t - off];
    __syncthreads();
    lds[t] = val;
    __syncthreads();
  }
  if (t < nb) bsum[t] = lds[t] - v;
}

__global__ __launch_bounds__(256) void k_scan3(int* __restrict__ exc,
                                               const int* __restrict__ bsum, int n) {
  int i = blockIdx.x * blockDim.x + threadIdx.x;
  if (i < n) exc[i] += bsum[i >> 10];
}

__global__ __launch_bounds__(256) void k_fill(const int* __restrict__ src,
                                              const int* __restrict__ dst,
                                              const int* __restrict__ rowStart,
                                              int* __restrict__ fillPos,
                                              int* __restrict__ eSrc, int E) {
  int i = blockIdx.x * blockDim.x + threadIdx.x;
  int stride = gridDim.x * blockDim.x;
  for (; i < E; i += stride) {
    int d = dst[i];
    int p = rowStart[d] + atomicAdd(&fillPos[d], 1);
    eSrc[p] = src[i];
  }
}

// ---------------- bf16 prescale: s = bf16(dinv * h), 256B rows -------------

__global__ __launch_bounds__(256) void k_scale(const float* __restrict__ h,
                                               const float* __restrict__ dinv,
                                               uint4* __restrict__ s4, int nQuads) {
  int i = blockIdx.x * blockDim.x + threadIdx.x;
  int stride = gridDim.x * blockDim.x;
  for (; i < nQuads; i += stride) {
    int row = i >> 4;
    int q = i & 15;
    float dv = dinv[row];
    const float4* hp = (const float4*)&h[(size_t)row * 128 + 8 * q];
    float4 a = hp[0], b = hp[1];
    uint4 o;
    o.x = (unsigned)f2bf(dv * a.x) | ((unsigned)f2bf(dv * a.y) << 16);
    o.y = (unsigned)f2bf(dv * a.z) | ((unsigned)f2bf(dv * a.w) << 16);
    o.z = (unsigned)f2bf(dv * b.x) | ((unsigned)f2bf(dv * b.y) << 16);
    o.w = (unsigned)f2bf(dv * b.z) | ((unsigned)f2bf(dv * b.w) << 16);
    s4[i] = o;
  }
}

// -------- fused layer: 2 edges per VMEM instruction, uint2(8B)/lane --------
// Lane l: half = l>>5, sl = l&31. Lane owns bf16 cols 4*sl..4*sl+3.
// Pair step: half 0 gathers edge A's 256B row, half 1 edge B's.
// Cross-half sum via shfl_xor(32); t[4q+r] lives in lane q (and q+32), reg r.
template <int NFO, bool RELU>
__global__ __launch_bounds__(512) void k_layer_bf2(const unsigned* __restrict__ sU,
                                                   const float* __restrict__ W,
                                                   const float* __restrict__ bias,
                                                   const float* __restrict__ dinv,
                                                   const int* __restrict__ eSrc,
                                                   const int* __restrict__ rowStart,
                                                   const int* __restrict__ cnt,
                                                   float* __restrict__ out, int n) {
  __shared__ float Wl[128 * NFO];
  for (int t = threadIdx.x; t < 128 * NFO; t += 512) Wl[t] = W[t];
  __syncthreads();
  const int wid = threadIdx.x >> 6, lane = threadIdx.x & 63;
  const int half = lane >> 5, sl = lane & 31;
  for (int node = blockIdx.x * 8 + wid; node < n; node += gridDim.x * 8) {
    const int st = rowStart[node], c = cnt[node];
    const int* es = eSrc + st;
    const float dv = dinv[node];
    uint2 vs = *(const uint2*)&sU[(size_t)node * 64 + 2 * sl];  // self row
    float a0, a1, a2, a3;
    if (half == 0) {
      a0 = bfLo(vs.x); a1 = bfHi(vs.x); a2 = bfLo(vs.y); a3 = bfHi(vs.y);
    } else {
      a0 = a1 = a2 = a3 = 0.f;
    }
    const int cl = c < 64 ? c : 64;
    int myIdx = (lane < cl) ? es[lane] : 0;
    int j = 0;
    for (; j + 8 <= cl; j += 8) {  // 4 pairs = 8 edges, loads independent
      int iA0 = __shfl(myIdx, j + 0), iB0 = __shfl(myIdx, j + 1);
      int iA1 = __shfl(myIdx, j + 2), iB1 = __shfl(myIdx, j + 3);
      int iA2 = __shfl(myIdx, j + 4), iB2 = __shfl(myIdx, j + 5);
      int iA3 = __shfl(myIdx, j + 6), iB3 = __shfl(myIdx, j + 7);
      int x0 = half ? iB0 : iA0;
      int x1 = half ? iB1 : iA1;
      int x2 = half ? iB2 : iA2;
      int x3 = half ? iB3 : iA3;
      uint2 v0 = *(const uint2*)&sU[(size_t)x0 * 64 + 2 * sl];
      uint2 v1 = *(const uint2*)&sU[(size_t)x1 * 64 + 2 * sl];
      uint2 v2 = *(const uint2*)&sU[(size_t)x2 * 64 + 2 * sl];
      uint2 v3 = *(const uint2*)&sU[(size_t)x3 * 64 + 2 * sl];
      a0 += bfLo(v0.x); a1 += bfHi(v0.x); a2 += bfLo(v0.y); a3 += bfHi(v0.y);
      a0 += bfLo(v1.x); a1 += bfHi(v1.x); a2 += bfLo(v1.y); a3 += bfHi(v1.y);
      a0 += bfLo(v2.x); a1 += bfHi(v2.x); a2 += bfLo(v2.y); a3 += bfHi(v2.y);
      a0 += bfLo(v3.x); a1 += bfHi(v3.x); a2 += bfLo(v3.y); a3 += bfHi(v3.y);
    }
    for (; j < c; j += 2) {  // pair tail (handles odd c and c>64)
      int iA = (j < cl) ? __shfl(myIdx, j) : es[j];
      int hasB = (j + 1 < c);
      int iB = hasB ? ((j + 1 < cl) ? __shfl(myIdx, j + 1) : es[j + 1]) : iA;
      int x = half ? iB : iA;
      uint2 v = *(const uint2*)&sU[(size_t)x * 64 + 2 * sl];
      if (half && !hasB) { v.x = 0u; v.y = 0u; }
      a0 += bfLo(v.x); a1 += bfHi(v.x); a2 += bfLo(v.y); a3 += bfHi(v.y);
    }
    // combine halves: both end with the full sum
    a0 += __shfl_xor(a0, 32);
    a1 += __shfl_xor(a1, 32);
    a2 += __shfl_xor(a2, 32);
    a3 += __shfl_xor(a3, 32);
    a0 *= dv; a1 *= dv; a2 *= dv; a3 *= dv;  // t[4*sl + r]
    // row-GEMM: out_col = sum_k t[k] * W[k][col]; t[4q+r] read from lane q
    if constexpr (NFO == 128) {
      float o0 = 0.f, o1 = 0.f;
      #pragma unroll
      for (int q = 0; q < 32; q++) {
        float t0 = __shfl(a0, q);
        float t1 = __shfl(a1, q);
        float t2 = __shfl(a2, q);
        float t3 = __shfl(a3, q);
        float2 w0 = *(const float2*)&Wl[(4 * q + 0) * 128 + 2 * lane];
        float2 w1 = *(const float2*)&Wl[(4 * q + 1) * 128 + 2 * lane];
        float2 w2 = *(const float2*)&Wl[(4 * q + 2) * 128 + 2 * lane];
        float2 w3 = *(const float2*)&Wl[(4 * q + 3) * 128 + 2 * lane];
        o0 = fmaf(t0, w0.x, o0); o1 = fmaf(t0, w0.y, o1);
        o0 = fmaf(t1, w1.x, o0); o1 = fmaf(t1, w1.y, o1);
        o0 = fmaf(t2, w2.x, o0); o1 = fmaf(t2, w2.y, o1);
        o0 = fmaf(t3, w3.x, o0); o1 = fmaf(t3, w3.y, o1);
      }
      float2 bb = *(const float2*)&bias[2 * lane];
      float r0 = o0 + bb.x, r1 = o1 + bb.y;
      if (RELU) { r0 = fmaxf(r0, 0.f); r1 = fmaxf(r1, 0.f); }
      *(float2*)&out[(size_t)node * 128 + 2 * lane] = make_float2(r0, r1);
    } else {
      float o0 = 0.f;
      #pragma unroll
      for (int q = 0; q < 32; q++) {
        float t0 = __shfl(a0, q);
        float t1 = __shfl(a1, q);
        float t2 = __shfl(a2, q);
        float t3 = __shfl(a3, q);
        o0 = fmaf(t0, Wl[(4 * q + 0) * NFO + lane], o0);
        o0 = fmaf(t1, Wl[(4 * q + 1) * NFO + lane], o0);
        o0 = fmaf(t2, Wl[(4 * q + 2) * NFO + lane], o0);
        o0 = fmaf(t3, Wl[(4 * q + 3) * NFO + lane], o0);
      }
      float r0 = o0 + bias[lane];
      if (RELU) r0 = fmaxf(r0, 0.f);
      out[(size_t)node * NFO + lane] = r0;
    }
  }
}

// --------------------- fp32 fused kernel (ws-fallback) ---------------------

template <int NFO, bool RELU>
__global__ __launch_bounds__(512) void k_layer_f32(const float* __restrict__ in,
                                                   const float* __restrict__ W,
                                                   const float* __restrict__ bias,
                                                   const float* __restrict__ dinv,
                                                   const int* __restrict__ eSrc,
                                                   const int* __restrict__ rowStart,
                                                   const int* __restrict__ cnt,
                                                   float* __restrict__ out, int n) {
  __shared__ float Wl[128 * NFO];
  for (int t = threadIdx.x; t < 128 * NFO; t += 512) Wl[t] = W[t];
  __syncthreads();
  const int wid = threadIdx.x >> 6, lane = threadIdx.x & 63;
  for (int node = blockIdx.x * 8 + wid; node < n; node += gridDim.x * 8) {
    const int s = rowStart[node], c = cnt[node];
    const int* es = eSrc + s;
    const float dv = dinv[node];
    float2 x2 = *(const float2*)&in[(size_t)node * 128 + 2 * lane];
    float ax = dv * x2.x, ay = dv * x2.y;
    int j = 0;
    for (; j + 4 <= c; j += 4) {
      int s0 = es[j], s1 = es[j + 1], s2 = es[j + 2], s3 = es[j + 3];
      float d0 = dinv[s0], d1 = dinv[s1], d2 = dinv[s2], d3 = dinv[s3];
      float2 v0 = *(const float2*)&in[(size_t)s0 * 128 + 2 * lane];
      float2 v1 = *(const float2*)&in[(size_t)s1 * 128 + 2 * lane];
      float2 v2 = *(const float2*)&in[(size_t)s2 * 128 + 2 * lane];
      float2 v3 = *(const float2*)&in[(size_t)s3 * 128 + 2 * lane];
      ax = fmaf(d0, v0.x, ax); ay = fmaf(d0, v0.y, ay);
      ax = fmaf(d1, v1.x, ax); ay = fmaf(d1, v1.y, ay);
      ax = fmaf(d2, v2.x, ax); ay = fmaf(d2, v2.y, ay);
      ax = fmaf(d3, v3.x, ax); ay = fmaf(d3, v3.y, ay);
    }
    for (; j < c; j++) {
      int sj = es[j];
      float dj = dinv[sj];
      float2 v = *(const float2*)&in[(size_t)sj * 128 + 2 * lane];
      ax = fmaf(dj, v.x, ax); ay = fmaf(dj, v.y, ay);
    }
    ax *= dv; ay *= dv;
    if constexpr (NFO == 128) {
      float o0 = 0.f, o1 = 0.f;
      #pragma unroll
      for (int kk = 0; kk < 64; kk++) {
        float xa = __shfl(ax, kk);
        float xb = __shfl(ay, kk);
        float2 wA = *(const float2*)&Wl[(2 * kk) * 128 + 2 * lane];
        float2 wB = *(const float2*)&Wl[(2 * kk + 1) * 128 + 2 * lane];
        o0 = fmaf(xa, wA.x, o0); o1 = fmaf(xa, wA.y, o1);
        o0 = fmaf(xb, wB.x, o0); o1 = fmaf(xb, wB.y, o1);
      }
      float2 bb = *(const float2*)&bias[2 * lane];
      float r0 = o0 + bb.x, r1 = o1 + bb.y;
      if (RELU) { r0 = fmaxf(r0, 0.f); r1 = fmaxf(r1, 0.f); }
      *(float2*)&out[(size_t)node * 128 + 2 * lane] = make_float2(r0, r1);
    } else {
      float o0 = 0.f;
      #pragma unroll
      for (int kk = 0; kk < 64; kk++) {
        float xa = __shfl(ax, kk);
        float xb = __shfl(ay, kk);
        o0 = fmaf(xa, Wl[(2 * kk) * NFO + lane], o0);
        o0 = fmaf(xb, Wl[(2 * kk + 1) * NFO + lane], o0);
      }
      float r0 = o0 + bias[lane];
      if (RELU) r0 = fmaxf(r0, 0.f);
      out[(size_t)node * NFO + lane] = r0;
    }
  }
}

// ---------------------------------------------------------------------------

extern "C" void kernel_launch(void* const* d_in, const int* in_sizes, int n_in,
                              void* d_out, int out_size, void* d_ws, size_t ws_size,
                              hipStream_t stream) {
  const float* x  = (const float*)d_in[0];
  const int*   ei = (const int*)d_in[1];
  const float* W1 = (const float*)d_in[2];
  const float* b1 = (const float*)d_in[3];
  const float* W2 = (const float*)d_in[4];
  const float* b2 = (const float*)d_in[5];
  const float* W3 = (const float*)d_in[6];
  const float* b3 = (const float*)d_in[7];

  const int N = in_sizes[0] / 128;
  const int E = in_sizes[1] / 2;
  const int* src = ei;
  const int* dst = ei + E;

  char* ws = (char*)d_ws;
  size_t off = 0;
  auto alloc = [&](size_t bytes) -> void* {
    void* p = ws + off;
    off = (off + bytes + 255) & ~(size_t)255;
    return p;
  };
  int*   cnt      = (int*)alloc((size_t)N * 4);
  int*   fillPos  = (int*)alloc((size_t)N * 4);
  int*   rowStart = (int*)alloc((size_t)N * 4);
  float* dinv     = (float*)alloc((size_t)N * 4);
  int*   bsum     = (int*)alloc(512);
  int*   eSrc     = (int*)alloc((size_t)E * 4);
  unsigned* sU    = (unsigned*)alloc((size_t)N * 64 * 4);  // bf16 rows, 256B
  const bool fast = (ws_size >= off);                       // ~33.7 MB

  float* y    = (float*)d_out;          // [N,64]
  float* out1 = y + (size_t)N * 64;     // [N,128]
  float* out2 = out1 + (size_t)N * 128; // [N,128]

  // ---- CSR build ----
  k_zero<<<(N + 255) / 256, 256, 0, stream>>>(cnt, fillPos, N);
  k_deg<<<2048, 256, 0, stream>>>(dst, cnt, E);
  k_dinv<<<(N + 255) / 256, 256, 0, stream>>>(cnt, dinv, N);
  int nChunks = (N + 1023) / 1024;
  k_scan1<<<nChunks, 256, 0, stream>>>(cnt, rowStart, bsum, N);
  k_scan2<<<1, 128, 0, stream>>>(bsum, nChunks);
  k_scan3<<<(N + 255) / 256, 256, 0, stream>>>(rowStart, bsum, N);
  k_fill<<<2048, 256, 0, stream>>>(src, dst, rowStart, fillPos, eSrc, E);

  // ---- layers ----
  if (fast) {
    const int nQuads = N * 16;
    const int sBlocks = (nQuads + 255) / 256;
    k_scale<<<sBlocks, 256, 0, stream>>>(x, dinv, (uint4*)sU, nQuads);
    k_layer_bf2<128, true ><<<1024, 512, 0, stream>>>(sU, W1, b1, dinv, eSrc, rowStart, cnt, out1, N);
    k_scale<<<sBlocks, 256, 0, stream>>>(out1, dinv, (uint4*)sU, nQuads);
    k_layer_bf2<128, true ><<<1024, 512, 0, stream>>>(sU, W2, b2, dinv, eSrc, rowStart, cnt, out2, N);
    k_scale<<<sBlocks, 256, 0, stream>>>(out2, dinv, (uint4*)sU, nQuads);
    k_layer_bf2<64,  false><<<1024, 512, 0, stream>>>(sU, W3, b3, dinv, eSrc, rowStart, cnt, y,    N);
  } else {
    k_layer_f32<128, true ><<<1024, 512, 0, stream>>>(x,    W1, b1, dinv, eSrc, rowStart, cnt, out1, N);
    k_layer_f32<128, true ><<<1024, 512, 0, stream>>>(out1, W2, b2, dinv, eSrc, rowStart, cnt, out2, N);
    k_layer_f32<64,  false><<<1024, 512, 0, stream>>>(out2, W3, b3, dinv, eSrc, rowStart, cnt, y,    N);
  }
}